// Round 17
// baseline (236.491 us; speedup 1.0000x reference)
//
#include <hip/hip_runtime.h>

#define NN 20000
#define EE 320000
#define RATIO_F 0.18257418583505536f   // 1/sqrt(30)
#define EPS_F 1e-6f
#define SCALE_D4 0.35355339059327373f  // 64^-0.25
#define NCH 157                        // ceil(20000/128) k3 chunks

typedef _Float16 f16x8 __attribute__((ext_vector_type(8)));
typedef _Float16 f16x4 __attribute__((ext_vector_type(4)));
typedef float f32x4 __attribute__((ext_vector_type(4)));

__device__ __forceinline__ unsigned fenc(float x) {
  unsigned u = __float_as_uint(x);
  return (u & 0x80000000u) ? ~u : (u | 0x80000000u);
}
__device__ __forceinline__ float fdec(unsigned u) {
  return (u & 0x80000000u) ? __uint_as_float(u & 0x7FFFFFFFu) : __uint_as_float(~u);
}
__device__ __forceinline__ void fma4(float* a, float s, float4 b) {
  a[0] = fmaf(s, b.x, a[0]);
  a[1] = fmaf(s, b.y, a[1]);
  a[2] = fmaf(s, b.z, a[2]);
  a[3] = fmaf(s, b.w, a[3]);
}
// async global->LDS, 16B per lane; LDS dest must be wave-uniform base + lane*16
__device__ __forceinline__ void gload16(const void* g, void* l) {
  __builtin_amdgcn_global_load_lds(
      (const __attribute__((address_space(1))) unsigned int*)g,
      (__attribute__((address_space(3))) unsigned int*)l, 16, 0, 0);
}

// =====================================================================
// K0 (merged): blocks 0-1023 fused weight plane Wf + bbig;
// 1024-1087 Wo hi/lo planes; 1088-1400 degree counts;
// 1401+ feat/z -> f16 conversion (consistent input perturbation).
// =====================================================================
__global__ __launch_bounds__(256)
void k0_build(const float* __restrict__ Wq, const float* __restrict__ Wk,
              const float* __restrict__ Wv, const float* __restrict__ bq,
              const float* __restrict__ bk, const float* __restrict__ bv,
              const float* __restrict__ proj, const float* __restrict__ tau,
              const float* __restrict__ Wo, const int* __restrict__ ei,
              const float* __restrict__ feat, const float* __restrict__ zin,
              _Float16* __restrict__ Wf, float* __restrict__ bbig,
              _Float16* __restrict__ WoFh, _Float16* __restrict__ WoFl,
              int* __restrict__ dini, int* __restrict__ douti,
              _Float16* __restrict__ feath, _Float16* __restrict__ zh16) {
  const int blk = blockIdx.x;
  const int i = threadIdx.x;   // k index
  if (blk >= 1401) {           // ---- f32 -> f16 conversions ----
    int cb = blk - 1401;
    const float* src;
    _Float16* dst;
    if (cb < 2500) { src = feat; dst = feath; }
    else           { src = zin;  dst = zh16; cb -= 2500; }
    const size_t off = (size_t)cb * 2048 + i * 8;
    const float4 a = *(const float4*)(src + off);
    const float4 b = *(const float4*)(src + off + 4);
    f16x8 o;
    o[0] = (_Float16)a.x; o[1] = (_Float16)a.y;
    o[2] = (_Float16)a.z; o[3] = (_Float16)a.w;
    o[4] = (_Float16)b.x; o[5] = (_Float16)b.y;
    o[6] = (_Float16)b.z; o[7] = (_Float16)b.w;
    *(f16x8*)(dst + off) = o;
    return;
  }
  if (blk >= 1088) {           // ---- degree counts (int4) ----
    const int q = (blk - 1088) * 256 + i;
    if (q < EE / 4) {
      const int4 r4 = *(const int4*)(ei + q * 4);
      const int4 c4 = *(const int4*)(ei + EE + q * 4);
      atomicAdd(&dini[c4.x], 1); atomicAdd(&dini[c4.y], 1);
      atomicAdd(&dini[c4.z], 1); atomicAdd(&dini[c4.w], 1);
      atomicAdd(&douti[r4.x], 1); atomicAdd(&douti[r4.y], 1);
      atomicAdd(&douti[r4.z], 1); atomicAdd(&douti[r4.w], 1);
    }
    return;
  }
  const int kt = i >> 5, gg = (i >> 3) & 3, j = i & 7;
  if (blk >= 1024) {           // ---- Wo planes ----
    const int col = blk - 1024;
    const float val = Wo[col * 256 + i];
    const int lane = gg * 16 + (col & 15);
    const size_t off = (size_t)((col >> 4) * 8 + kt) * 512 + lane * 8 + j;
    const _Float16 hb = (_Float16)val;
    WoFh[off] = hb;
    WoFl[off] = (_Float16)(val - (float)hb);
    return;
  }
  const int col = blk;
  const float s = rsqrtf(tau[0]) * SCALE_D4;
  float val = 0.f, bias = 0.f;
  if (col < 256) {
    val = Wq[col * 256 + i]; bias = bq[col];
  } else if (col < 512) {
    const int c = col - 256;
    val = Wk[c * 256 + i]; bias = bk[c];
  } else if (col < 768) {
    const int c = col - 512;
    val = Wv[c * 256 + i]; bias = bv[c];
  } else {
    const int rr = col - 768;
    const int grp = rr >> 7;             // 0 = q, 1 = k
    const int h = (rr >> 5) & 3, m = rr & 31;
    if (m < 30) {
      const float* W = grp ? Wk : Wq;
      const float* bb = grp ? bk : bq;
      float a = 0.f, ba = 0.f;
#pragma unroll 8
      for (int d = 0; d < 64; ++d) {
        const float pr = proj[m * 64 + d];
        a  = fmaf(pr, W[(h * 64 + d) * 256 + i], a);
        ba = fmaf(pr, bb[h * 64 + d], ba);
      }
      val = s * a; bias = s * ba;
    }
  }
  const int lane = gg * 16 + (col & 15);
  const size_t off = (size_t)((col >> 4) * 8 + kt) * 512 + lane * 8 + j;
  Wf[off] = (_Float16)val;
  if (i == 0) bbig[col] = bias;
}

// ---- ct index for slice slot s ----
__device__ __forceinline__ int ct_of(int s, int isv, int h, int y) {
  if (isv) return 32 + (y - 4) * 8 + s;
  if (s < 4)  return h * 4 + s;
  if (s < 8)  return 16 + h * 4 + (s - 4);
  if (s < 10) return 48 + 2 * h + (s - 8);
  return 56 + 2 * h + (s - 10);
}

// =====================================================================
// K1m (merged): blocks 0-941 = k1 GEMM slices (x = blk%157, y = blk/157);
// 942-1566 = CSR fill writing packed (row, rsqrt(douti)) int2 records.
// Quarter-K DOUBLE-BUFFERED B staging: stage q(i+1) issues at the top of
// iteration i and flies under i's ds_read+MFMA phase (one barrier/iter).
// =====================================================================
__global__ __launch_bounds__(512, 4)
void k1m(const _Float16* __restrict__ feath, const _Float16* __restrict__ zh16,
         const _Float16* __restrict__ Wf, const float* __restrict__ bbig,
         const float* __restrict__ tau,
         _Float16* __restrict__ qph, _Float16* __restrict__ kbufh,
         _Float16* __restrict__ vh, unsigned* __restrict__ kmaxU,
         const int* __restrict__ ei, const int* __restrict__ coff,
         int* __restrict__ cursor, int2* __restrict__ crowR,
         const int* __restrict__ douti) {
  __shared__ __align__(16) _Float16 blds[2][12 * 1024];   // 2 x 24 KB
  const int blk = blockIdx.x;
  const int t = threadIdx.x;
  if (blk >= 942) {            // ---- CSR fill (overlaps GEMM) ----
    const int e = (blk - 942) * 512 + t;
    const int r = ei[e], c = ei[EE + e];
    const float w = rsqrtf((float)douti[r]);
    const int pos = atomicAdd(&cursor[c], 1);
    int2 rec; rec.x = r; rec.y = __float_as_int(w);
    crowR[coff[c] + pos] = rec;
    return;
  }
  const int y = blk / 157;
  const int h = y & 3;
  const int wid = t >> 6, lane = t & 63;
  const int g = lane >> 4, cl = lane & 15;
  const int rbase = (blk - y * 157) * 128 + wid * 16;
  int arow = rbase + cl; if (arow > NN - 1) arow = NN - 1;

  if (y < 4) {
    const _Float16* arp = feath + (size_t)arow * 256;
    // ---- all A fragments upfront (8 x 16B in flight) ----
    f16x8 Ah[8];
#pragma unroll
    for (int l = 0; l < 8; ++l)
      Ah[l] = *(const f16x8*)(arp + l * 32 + g * 8);
    // ---- prologue: stage quarter 0 (kt 0,1 of 12 cts) into buf 0 ----
#pragma unroll
    for (int r = 0; r < 3; ++r) {
      const int idx = r * 4096 + t * 8;
      const int s = idx >> 10, wi = idx & 1023;
      gload16(Wf + (size_t)ct_of(s, 0, h, y) * 4096 + wi, &blds[0][idx]);
    }
    __syncthreads();

    f32x4 acc[12];
#pragma unroll
    for (int s = 0; s < 12; ++s) acc[s] = (f32x4){0.f, 0.f, 0.f, 0.f};

#pragma unroll
    for (int qi = 0; qi < 4; ++qi) {
      const int buf = qi & 1;
      if (qi < 3) {   // issue next-quarter stage; flies under this MFMA phase
#pragma unroll
        for (int r = 0; r < 3; ++r) {
          const int idx = r * 4096 + t * 8;
          const int s = idx >> 10, wi = idx & 1023;
          gload16(Wf + (size_t)ct_of(s, 0, h, y) * 4096 + (qi + 1) * 1024 + wi,
                  &blds[buf ^ 1][idx]);
        }
      }
#pragma unroll
      for (int ktl = 0; ktl < 2; ++ktl) {
        const f16x8 a = Ah[qi * 2 + ktl];
#pragma unroll
        for (int s = 0; s < 12; ++s) {
          const f16x8 b = *(const f16x8*)&blds[buf][s * 1024 + ktl * 512 + lane * 8];
          acc[s] = __builtin_amdgcn_mfma_f32_16x16x32_f16(a, b, acc[s], 0, 0, 0);
        }
      }
      __syncthreads();
    }

    // ---- epilogue (wave-local) ----
#pragma unroll
    for (int s = 0; s < 12; ++s) {
      const float bb = bbig[ct_of(s, 0, h, y) * 16 + cl];
#pragma unroll
      for (int j = 0; j < 4; ++j) acc[s][j] += bb;
    }
    const float sc = rsqrtf(tau[0]) * SCALE_D4;
    const float h2 = 0.5f * sc * sc;
    float dsq[4], dsk[4];
#pragma unroll
    for (int j = 0; j < 4; ++j) {
      dsq[j] = acc[0][j] * acc[0][j] + acc[1][j] * acc[1][j] +
               acc[2][j] * acc[2][j] + acc[3][j] * acc[3][j];
      dsk[j] = acc[4][j] * acc[4][j] + acc[5][j] * acc[5][j] +
               acc[6][j] * acc[6][j] + acc[7][j] * acc[7][j];
    }
#pragma unroll
    for (int m = 1; m < 16; m <<= 1) {
#pragma unroll
      for (int j = 0; j < 4; ++j) {
        dsq[j] += __shfl_xor(dsq[j], m);
        dsk[j] += __shfl_xor(dsk[j], m);
      }
    }
    {  // xd_q -> qph (f16)
#pragma unroll
      for (int j = 0; j < 4; ++j) {
        const float x0 = acc[8][j], x1 = acc[9][j];
        float mv = fmaxf(x0, (cl < 14) ? x1 : -3.4e38f);
#pragma unroll
        for (int m = 1; m < 16; m <<= 1) mv = fmaxf(mv, __shfl_xor(mv, m));
        const float dg = h2 * dsq[j];
        const int r = rbase + 4 * g + j;
        if (r < NN) {
          _Float16* dst = qph + (size_t)r * 120 + h * 30;
          dst[cl] = (_Float16)(RATIO_F * (expf(x0 - dg - mv) + EPS_F));
          if (cl < 14)
            dst[16 + cl] = (_Float16)(RATIO_F * (expf(x1 - dg - mv) + EPS_F));
        }
      }
    }
    {  // xd_k -> kbufh (f16) + global head max
      float wmax = -3.4e38f;
#pragma unroll
      for (int j = 0; j < 4; ++j) {
        const float x0 = acc[10][j], x1 = acc[11][j];
        float mv = fmaxf(x0, (cl < 14) ? x1 : -3.4e38f);
#pragma unroll
        for (int m = 1; m < 16; m <<= 1) mv = fmaxf(mv, __shfl_xor(mv, m));
        wmax = fmaxf(wmax, mv);
        const float dg = h2 * dsk[j];
        const int r = rbase + 4 * g + j;
        if (r < NN) {
          _Float16* dst = kbufh + (size_t)r * 120 + h * 30;
          dst[cl] = (_Float16)(x0 - dg);
          if (cl < 14) dst[16 + cl] = (_Float16)(x1 - dg);
        }
      }
      wmax = fmaxf(wmax, __shfl_xor(wmax, 16));
      wmax = fmaxf(wmax, __shfl_xor(wmax, 32));
      if (lane == 0) atomicMax(&kmaxU[h], fenc(wmax));
    }
  } else {
    const _Float16* arp = zh16 + (size_t)arow * 256;
    f16x8 Ah[8];
#pragma unroll
    for (int l = 0; l < 8; ++l)
      Ah[l] = *(const f16x8*)(arp + l * 32 + g * 8);
    // ---- prologue: stage quarter 0 (kt 0,1 of 8 cts) into buf 0 ----
#pragma unroll
    for (int r = 0; r < 2; ++r) {
      const int idx = r * 4096 + t * 8;
      const int s = idx >> 10, wi = idx & 1023;
      gload16(Wf + (size_t)ct_of(s, 1, h, y) * 4096 + wi, &blds[0][idx]);
    }
    __syncthreads();

    f32x4 acc[8];
#pragma unroll
    for (int s = 0; s < 8; ++s) acc[s] = (f32x4){0.f, 0.f, 0.f, 0.f};

#pragma unroll
    for (int qi = 0; qi < 4; ++qi) {
      const int buf = qi & 1;
      if (qi < 3) {
#pragma unroll
        for (int r = 0; r < 2; ++r) {
          const int idx = r * 4096 + t * 8;
          const int s = idx >> 10, wi = idx & 1023;
          gload16(Wf + (size_t)ct_of(s, 1, h, y) * 4096 + (qi + 1) * 1024 + wi,
                  &blds[buf ^ 1][idx]);
        }
      }
#pragma unroll
      for (int ktl = 0; ktl < 2; ++ktl) {
        const f16x8 a = Ah[qi * 2 + ktl];
#pragma unroll
        for (int s = 0; s < 8; ++s) {
          const f16x8 b = *(const f16x8*)&blds[buf][s * 1024 + ktl * 512 + lane * 8];
          acc[s] = __builtin_amdgcn_mfma_f32_16x16x32_f16(a, b, acc[s], 0, 0, 0);
        }
      }
      __syncthreads();
    }

#pragma unroll
    for (int s = 0; s < 8; ++s) {
      const int ct = ct_of(s, 1, h, y);
      const float bb = bbig[ct * 16 + cl];
      const int colb = (ct - 32) * 16 + cl;
#pragma unroll
      for (int j = 0; j < 4; ++j) {
        const int r = rbase + 4 * g + j;
        if (r < NN) vh[(size_t)r * 256 + colb] = (_Float16)(acc[s][j] + bb);
      }
    }
  }
}

// ------------- K3a: per-chunk partials of kvs/ksum (no atomics) -------------
__global__ __launch_bounds__(256)
void k3_kvs(const _Float16* __restrict__ kbr, const _Float16* __restrict__ vh,
            const unsigned* __restrict__ kmaxU, float* __restrict__ partial) {
  __shared__ float kpch[128 * 32];
  __shared__ float vch[128 * 68];
  const int h = blockIdx.y;
  const int n0 = blockIdx.x * 128;
  const int cnt = min(128, NN - n0);
  const int t = threadIdx.x;
  const float mx = fdec(kmaxU[h]);
  const int m = t >> 3, dg = t & 7, d0 = dg * 8;
#pragma unroll
  for (int l = 0; l < 15; ++l) {
    const int flat = l * 256 + t;
    const int nl = flat / 30, mm = flat - nl * 30;
    kpch[nl * 32 + mm] = (nl < cnt)
        ? RATIO_F * (expf((float)kbr[(size_t)(n0 + nl) * 120 + h * 30 + mm] - mx) + EPS_F)
        : 0.f;
  }
#pragma unroll
  for (int l = 0; l < 8; ++l) {
    const int f4 = l * 256 + t;
    const int nl = f4 >> 4, dd = (f4 & 15) * 4;
    float4 vv = make_float4(0.f, 0.f, 0.f, 0.f);
    if (nl < cnt) {
      f16x4 u = *(const f16x4*)(vh + (size_t)(n0 + nl) * 256 + h * 64 + dd);
      vv = make_float4((float)u[0], (float)u[1], (float)u[2], (float)u[3]);
    }
    *(float4*)&vch[nl * 68 + dd] = vv;
  }
  __syncthreads();
  float acc[8] = {0, 0, 0, 0, 0, 0, 0, 0};
  float asum = 0.f;
  const int ms = (m < 30) ? m : 0;
  for (int nl = 0; nl < cnt; ++nl) {
    const float kv = kpch[nl * 32 + ms];
    const float4 va = *(const float4*)&vch[nl * 68 + d0];
    const float4 vb = *(const float4*)&vch[nl * 68 + d0 + 4];
    fma4(&acc[0], kv, va);
    fma4(&acc[4], kv, vb);
    asum += kv;
  }
  if (m < 30) {
    float* dst = partial + ((size_t)blockIdx.y * NCH + blockIdx.x) * 1952 + m * 64 + d0;
#pragma unroll
    for (int j = 0; j < 8; ++j) dst[j] = acc[j];
    if (dg == 0)
      partial[((size_t)blockIdx.y * NCH + blockIdx.x) * 1952 + 1920 + m] = asum;
  }
}

// =====================================================================
// K7g3b (merged): blocks 0-4999 gather via packed records -> aggh;
// 5000+ reduce partials -> kvs/ksum.
// =====================================================================
__global__ __launch_bounds__(256)
void k7g3b(const int* __restrict__ coff, const int2* __restrict__ crowR,
           const _Float16* __restrict__ vh, _Float16* __restrict__ aggh,
           const float* __restrict__ partial, float* __restrict__ kvs,
           float* __restrict__ ksum) {
  const int blk = blockIdx.x;
  if (blk >= 5000) {           // ---- k3b reduce ----
    const int idx = (blk - 5000) * 256 + threadIdx.x;
    if (idx >= 4 * 1952) return;
    const int h = idx / 1952, q = idx - h * 1952;
    float s = 0.f;
    for (int c = 0; c < NCH; ++c)
      s += partial[((size_t)h * NCH + c) * 1952 + q];
    if (q < 1920) kvs[h * 1920 + q] = s;
    else if (q < 1950) ksum[h * 30 + (q - 1920)] = s;
    return;
  }
  const int node = blk * 4 + (threadIdx.x >> 6);
  const int lane = threadIdx.x & 63;
  const int o0 = coff[node], o1 = coff[node + 1];
  float a0 = 0.f, a1 = 0.f, a2 = 0.f, a3 = 0.f;
  if (o1 > o0) {
    int e = o0;
    for (; e + 16 <= o1; e += 16) {
      int2 rc[16];
#pragma unroll
      for (int u = 0; u < 16; ++u) rc[u] = crowR[e + u];
#pragma unroll
      for (int u = 0; u < 16; ++u) {
        const float w = __int_as_float(rc[u].y);
        const f16x4 vv = *(const f16x4*)(vh + (size_t)rc[u].x * 256 + lane * 4);
        a0 = fmaf(w, (float)vv[0], a0);
        a1 = fmaf(w, (float)vv[1], a1);
        a2 = fmaf(w, (float)vv[2], a2);
        a3 = fmaf(w, (float)vv[3], a3);
      }
    }
    for (; e + 4 <= o1; e += 4) {
      int2 rc[4];
#pragma unroll
      for (int u = 0; u < 4; ++u) rc[u] = crowR[e + u];
#pragma unroll
      for (int u = 0; u < 4; ++u) {
        const float w = __int_as_float(rc[u].y);
        const f16x4 vv = *(const f16x4*)(vh + (size_t)rc[u].x * 256 + lane * 4);
        a0 = fmaf(w, (float)vv[0], a0);
        a1 = fmaf(w, (float)vv[1], a1);
        a2 = fmaf(w, (float)vv[2], a2);
        a3 = fmaf(w, (float)vv[3], a3);
      }
    }
    for (; e < o1; ++e) {
      const int2 rc = crowR[e];
      const float w = __int_as_float(rc.y);
      const f16x4 vv = *(const f16x4*)(vh + (size_t)rc.x * 256 + lane * 4);
      a0 = fmaf(w, (float)vv[0], a0);
      a1 = fmaf(w, (float)vv[1], a1);
      a2 = fmaf(w, (float)vv[2], a2);
      a3 = fmaf(w, (float)vv[3], a3);
    }
    const float rin = rsqrtf((float)(o1 - o0));
    a0 *= rin; a1 *= rin; a2 *= rin; a3 *= rin;
  }
  f16x4 st;
  st[0] = (_Float16)a0; st[1] = (_Float16)a1;
  st[2] = (_Float16)a2; st[3] = (_Float16)a3;
  *(f16x4*)(aggh + (size_t)node * 256 + lane * 4) = st;
}

// ------------- K4: num/den + sg*agg -> zh (f16) -------------
__global__ __launch_bounds__(256)
void k4_attn(const _Float16* __restrict__ qph, const float* __restrict__ kvs,
             const float* __restrict__ ksum, const _Float16* __restrict__ aggh,
             const float* __restrict__ bp, _Float16* __restrict__ zh) {
  __shared__ float kvsl[120 * 68];
  __shared__ float ksl[120];
  __shared__ float qpl[32 * 120];
  const int t = threadIdx.x;
  const int n0 = blockIdx.x * 32;
#pragma unroll
  for (int l = 0; l < 30; ++l) {
    const int f = l * 256 + t;           // 7680
    const int hm = f >> 6, d = f & 63;
    kvsl[hm * 68 + d] = kvs[f];
  }
  if (t < 120) ksl[t] = ksum[t];
#pragma unroll
  for (int l = 0; l < 15; ++l) {
    const int f = l * 256 + t;           // 3840
    qpl[f] = (float)qph[(size_t)n0 * 120 + f];
  }
  __syncthreads();
  const int nl = t >> 3, dg = t & 7, d0 = dg * 8;
  const float* qrow = &qpl[nl * 120];
  float den[4] = {0, 0, 0, 0};
  for (int m = 0; m < 30; ++m) {
#pragma unroll
    for (int hh = 0; hh < 4; ++hh) den[hh] = fmaf(qrow[hh * 30 + m], ksl[hh * 30 + m], den[hh]);
  }
  float acc[4][8] = {};
  for (int m = 0; m < 30; ++m) {
#pragma unroll
    for (int hh = 0; hh < 4; ++hh) {
      const float qv = qrow[hh * 30 + m];
      const float* kr = &kvsl[(hh * 30 + m) * 68 + d0];
      const float4 ka = *(const float4*)kr;
      const float4 kb = *(const float4*)(kr + 4);
      fma4(&acc[hh][0], qv, ka);
      fma4(&acc[hh][4], qv, kb);
    }
  }
  const size_t n = n0 + nl;
#pragma unroll
  for (int hh = 0; hh < 4; ++hh) {
    const float inv = 1.0f / den[hh];
    const float sg = 1.f / (1.f + expf(-bp[hh]));
    const f16x8 ag = *(const f16x8*)(aggh + n * 256 + hh * 64 + d0);
    f16x8 o;
#pragma unroll
    for (int jj = 0; jj < 8; ++jj)
      o[jj] = (_Float16)(acc[hh][jj] * inv + sg * (float)ag[jj]);
    *(f16x8*)(zh + n * 256 + hh * 64 + d0) = o;
  }
}

// ------------- K6a: exclusive scan of in-degrees (1024 threads, int4) -------------
__global__ __launch_bounds__(1024)
void k6a_scan(const int* __restrict__ cnt, int* __restrict__ off) {
  __shared__ int s[1024];
  const int t = threadIdx.x;
  int4 v[5];
  int sum = 0;
  const int4* p4 = (const int4*)(cnt + t * 20);
#pragma unroll
  for (int i = 0; i < 5; ++i) {
    v[i] = p4[i];
    sum += v[i].x + v[i].y + v[i].z + v[i].w;
  }
  s[t] = sum;
  __syncthreads();
  for (int o = 1; o < 1024; o <<= 1) {
    const int add = (t >= o) ? s[t - o] : 0;
    __syncthreads();
    s[t] += add;
    __syncthreads();
  }
  int run = (t == 0) ? 0 : s[t - 1];
  if (t == 0) off[0] = 0;
  const int base = t * 20;
#pragma unroll
  for (int i = 0; i < 5; ++i) {
    const int vals[4] = {v[i].x, v[i].y, v[i].z, v[i].w};
#pragma unroll
    for (int j = 0; j < 4; ++j) {
      const int idx = base + i * 4 + j;
      if (idx < NN) { run += vals[j]; off[idx + 1] = run; }
    }
  }
}

// =====================================================================
// K8m: out = zh @ Wo^T + bo via MFMA (2-term B hi/lo, A exact f16).
// 628 blocks x 32 rows; 8 waves = 2 row-tiles x 4 cts.
// =====================================================================
__global__ __launch_bounds__(512, 4)
void k8m_out(const _Float16* __restrict__ zh, const _Float16* __restrict__ WoFh,
             const _Float16* __restrict__ WoFl, const float* __restrict__ bo,
             float* __restrict__ out) {
  __shared__ __align__(16) _Float16 blds[8 * 4096];   // 64 KB: 0-3 hi, 4-7 lo
  const int t = threadIdx.x;
  const int wid = t >> 6, lane = t & 63;
  const int g = lane >> 4, cl = lane & 15;
  const int rt = wid >> 2, ct = wid & 3;
  const int rbase = blockIdx.x * 32 + rt * 16;
  int arow = rbase + cl; if (arow > NN - 1) arow = NN - 1;
#pragma unroll
  for (int s = 0; s < 4; ++s) {
    gload16(WoFh + (size_t)s * 4096 + t * 8, &blds[(s * 512 + t) * 8]);
    gload16(WoFl + (size_t)s * 4096 + t * 8, &blds[((s + 4) * 512 + t) * 8]);
  }
  const _Float16* zr = zh + (size_t)arow * 256;
  f16x8 Ah[8];
#pragma unroll
  for (int kt = 0; kt < 8; ++kt)
    Ah[kt] = *(const f16x8*)(zr + kt * 32 + g * 8);
  __syncthreads();
  f32x4 acc = {0.f, 0.f, 0.f, 0.f};
#pragma unroll
  for (int kt = 0; kt < 8; ++kt) {
    const f16x8 bh = *(const f16x8*)&blds[ct * 4096 + kt * 512 + lane * 8];
    const f16x8 bl = *(const f16x8*)&blds[(ct + 4) * 4096 + kt * 512 + lane * 8];
    acc = __builtin_amdgcn_mfma_f32_16x16x32_f16(Ah[kt], bh, acc, 0, 0, 0);
    acc = __builtin_amdgcn_mfma_f32_16x16x32_f16(Ah[kt], bl, acc, 0, 0, 0);
  }
  const float bb = bo[ct * 16 + cl];
#pragma unroll
  for (int j = 0; j < 4; ++j) {
    const int r = rbase + 4 * g + j;
    if (r < NN) out[(size_t)r * 64 + ct * 16 + cl] = acc[j] + bb;
  }
}

extern "C" void kernel_launch(void* const* d_in, const int* in_sizes, int n_in,
                              void* d_out, int out_size, void* d_ws, size_t ws_size,
                              hipStream_t stream) {
  (void)in_sizes; (void)n_in; (void)out_size; (void)ws_size;
  const float* z    = (const float*)d_in[0];
  const float* feat = (const float*)d_in[1];
  const int*   ei   = (const int*)d_in[2];
  const float* tau  = (const float*)d_in[3];
  const float* Wq_w = (const float*)d_in[4];
  const float* Wq_b = (const float*)d_in[5];
  const float* Wk_w = (const float*)d_in[6];
  const float* Wk_b = (const float*)d_in[7];
  const float* Wv_w = (const float*)d_in[8];
  const float* Wv_b = (const float*)d_in[9];
  const float* Wo_w = (const float*)d_in[10];
  const float* Wo_b = (const float*)d_in[11];
  const float* bp   = (const float*)d_in[12];
  const float* proj = (const float*)d_in[13];
  float* out = (float*)d_out;

  char* p = (char*)d_ws;
  auto alloc = [&](size_t bytes) { char* r = p; p += (bytes + 255) & ~(size_t)255; return r; };
  _Float16* Wf    = (_Float16*)alloc((size_t)256 * 1024 * 2);
  _Float16* WoFh  = (_Float16*)alloc((size_t)64 * 256 * 2);
  _Float16* WoFl  = (_Float16*)alloc((size_t)64 * 256 * 2);
  float*    bbig  = (float*)alloc(1024 * 4);
  _Float16* feath = (_Float16*)alloc((size_t)NN * 256 * 2);
  _Float16* zh16  = (_Float16*)alloc((size_t)NN * 256 * 2);
  _Float16* vh    = (_Float16*)alloc((size_t)NN * 256 * 2);
  _Float16* aggh  = (_Float16*)alloc((size_t)NN * 256 * 2);
  _Float16* qph   = (_Float16*)alloc((size_t)NN * 120 * 2);
  _Float16* kbufh = (_Float16*)alloc((size_t)NN * 120 * 2);
  _Float16* zh    = (_Float16*)alloc((size_t)NN * 256 * 2);
  int2*     crowR = (int2*)alloc((size_t)EE * 8);
  int*      coff  = (int*)alloc((size_t)(NN + 1) * 4);
  float*    partial = (float*)alloc((size_t)4 * NCH * 1952 * 4);
  float*    kvs   = (float*)alloc(7680 * 4);
  float*    ksum  = (float*)alloc(120 * 4);
  // ---- contiguous zero-region ----
  char* z0 = p;
  unsigned* kmaxU = (unsigned*)alloc(16);
  int*      dini  = (int*)alloc((size_t)20480 * 4);   // padded for int4 scan
  int*      douti = (int*)alloc((size_t)NN * 4);
  int*      cursor= (int*)alloc((size_t)NN * 4);
  char* z1 = p;

  hipMemsetAsync(z0, 0, (size_t)(z1 - z0), stream);

  k0_build<<<1401 + 5000, 256, 0, stream>>>(
      Wq_w, Wk_w, Wv_w, Wq_b, Wk_b, Wv_b, proj, tau, Wo_w, ei, feat, z,
      Wf, bbig, WoFh, WoFl, dini, douti, feath, zh16);
  k6a_scan<<<1, 1024, 0, stream>>>(dini, coff);
  k1m<<<1567, 512, 0, stream>>>(feath, zh16, Wf, bbig, tau, qph, kbufh, vh,
                                kmaxU, ei, coff, cursor, crowR, douti);
  k3_kvs<<<dim3(NCH, 4), 256, 0, stream>>>(kbufh, vh, kmaxU, partial);
  k7g3b<<<5000 + (4 * 1952 + 255) / 256, 256, 0, stream>>>(
      coff, crowR, vh, aggh, partial, kvs, ksum);
  k4_attn<<<NN / 32, 256, 0, stream>>>(qph, kvs, ksum, aggh, bp, zh);
  k8m_out<<<628, 512, 0, stream>>>(zh, WoFh, WoFl, Wo_b, out);
}

// Round 18
// 228.966 us; speedup vs baseline: 1.0329x; 1.0329x over previous
//
#include <hip/hip_runtime.h>

#define NN 20000
#define EE 320000
#define RATIO_F 0.18257418583505536f   // 1/sqrt(30)
#define EPS_F 1e-6f
#define SCALE_D4 0.35355339059327373f  // 64^-0.25
#define NCH 157                        // ceil(20000/128) k3 chunks

typedef _Float16 f16x8 __attribute__((ext_vector_type(8)));
typedef _Float16 f16x4 __attribute__((ext_vector_type(4)));
typedef float f32x4 __attribute__((ext_vector_type(4)));

__device__ __forceinline__ unsigned fenc(float x) {
  unsigned u = __float_as_uint(x);
  return (u & 0x80000000u) ? ~u : (u | 0x80000000u);
}
__device__ __forceinline__ float fdec(unsigned u) {
  return (u & 0x80000000u) ? __uint_as_float(u & 0x7FFFFFFFu) : __uint_as_float(~u);
}
__device__ __forceinline__ void fma4(float* a, float s, float4 b) {
  a[0] = fmaf(s, b.x, a[0]);
  a[1] = fmaf(s, b.y, a[1]);
  a[2] = fmaf(s, b.z, a[2]);
  a[3] = fmaf(s, b.w, a[3]);
}
// async global->LDS, 16B per lane; LDS dest must be wave-uniform base + lane*16
__device__ __forceinline__ void gload16(const void* g, void* l) {
  __builtin_amdgcn_global_load_lds(
      (const __attribute__((address_space(1))) unsigned int*)g,
      (__attribute__((address_space(3))) unsigned int*)l, 16, 0, 0);
}

// =====================================================================
// K0 (merged): blocks 0-1023 fused weight plane Wf + bbig;
// 1024-1087 Wo hi/lo planes; 1088-1400 degree counts;
// 1401+ feat/z -> f16 conversion (consistent input perturbation).
// =====================================================================
__global__ __launch_bounds__(256)
void k0_build(const float* __restrict__ Wq, const float* __restrict__ Wk,
              const float* __restrict__ Wv, const float* __restrict__ bq,
              const float* __restrict__ bk, const float* __restrict__ bv,
              const float* __restrict__ proj, const float* __restrict__ tau,
              const float* __restrict__ Wo, const int* __restrict__ ei,
              const float* __restrict__ feat, const float* __restrict__ zin,
              _Float16* __restrict__ Wf, float* __restrict__ bbig,
              _Float16* __restrict__ WoFh,
              int* __restrict__ dini, int* __restrict__ douti,
              _Float16* __restrict__ feath, _Float16* __restrict__ zh16) {
  const int blk = blockIdx.x;
  const int i = threadIdx.x;   // k index
  if (blk >= 1401) {           // ---- f32 -> f16 conversions ----
    int cb = blk - 1401;
    const float* src;
    _Float16* dst;
    if (cb < 2500) { src = feat; dst = feath; }
    else           { src = zin;  dst = zh16; cb -= 2500; }
    const size_t off = (size_t)cb * 2048 + i * 8;
    const float4 a = *(const float4*)(src + off);
    const float4 b = *(const float4*)(src + off + 4);
    f16x8 o;
    o[0] = (_Float16)a.x; o[1] = (_Float16)a.y;
    o[2] = (_Float16)a.z; o[3] = (_Float16)a.w;
    o[4] = (_Float16)b.x; o[5] = (_Float16)b.y;
    o[6] = (_Float16)b.z; o[7] = (_Float16)b.w;
    *(f16x8*)(dst + off) = o;
    return;
  }
  if (blk >= 1088) {           // ---- degree counts (int4) ----
    const int q = (blk - 1088) * 256 + i;
    if (q < EE / 4) {
      const int4 r4 = *(const int4*)(ei + q * 4);
      const int4 c4 = *(const int4*)(ei + EE + q * 4);
      atomicAdd(&dini[c4.x], 1); atomicAdd(&dini[c4.y], 1);
      atomicAdd(&dini[c4.z], 1); atomicAdd(&dini[c4.w], 1);
      atomicAdd(&douti[r4.x], 1); atomicAdd(&douti[r4.y], 1);
      atomicAdd(&douti[r4.z], 1); atomicAdd(&douti[r4.w], 1);
    }
    return;
  }
  const int kt = i >> 5, gg = (i >> 3) & 3, j = i & 7;
  if (blk >= 1024) {           // ---- Wo plane (hi only) ----
    const int col = blk - 1024;
    const float val = Wo[col * 256 + i];
    const int lane = gg * 16 + (col & 15);
    const size_t off = (size_t)((col >> 4) * 8 + kt) * 512 + lane * 8 + j;
    WoFh[off] = (_Float16)val;
    return;
  }
  const int col = blk;
  const float s = rsqrtf(tau[0]) * SCALE_D4;
  float val = 0.f, bias = 0.f;
  if (col < 256) {
    val = Wq[col * 256 + i]; bias = bq[col];
  } else if (col < 512) {
    const int c = col - 256;
    val = Wk[c * 256 + i]; bias = bk[c];
  } else if (col < 768) {
    const int c = col - 512;
    val = Wv[c * 256 + i]; bias = bv[c];
  } else {
    const int rr = col - 768;
    const int grp = rr >> 7;             // 0 = q, 1 = k
    const int h = (rr >> 5) & 3, m = rr & 31;
    if (m < 30) {
      const float* W = grp ? Wk : Wq;
      const float* bb = grp ? bk : bq;
      float a = 0.f, ba = 0.f;
#pragma unroll 8
      for (int d = 0; d < 64; ++d) {
        const float pr = proj[m * 64 + d];
        a  = fmaf(pr, W[(h * 64 + d) * 256 + i], a);
        ba = fmaf(pr, bb[h * 64 + d], ba);
      }
      val = s * a; bias = s * ba;
    }
  }
  const int lane = gg * 16 + (col & 15);
  const size_t off = (size_t)((col >> 4) * 8 + kt) * 512 + lane * 8 + j;
  Wf[off] = (_Float16)val;
  if (i == 0) bbig[col] = bias;
}

// ---- ct index for slice slot s ----
__device__ __forceinline__ int ct_of(int s, int isv, int h, int y) {
  if (isv) return 32 + (y - 4) * 8 + s;
  if (s < 4)  return h * 4 + s;
  if (s < 8)  return 16 + h * 4 + (s - 4);
  if (s < 10) return 48 + 2 * h + (s - 8);
  return 56 + 2 * h + (s - 10);
}

// =====================================================================
// K1m (R16-best): blocks 0-941 = GEMM slices; 942-1566 = CSR fill
// writing packed (row, rsqrt(douti)) int2 records. Half-K staging.
// =====================================================================
__global__ __launch_bounds__(512, 4)
void k1m(const _Float16* __restrict__ feath, const _Float16* __restrict__ zh16,
         const _Float16* __restrict__ Wf, const float* __restrict__ bbig,
         const float* __restrict__ tau,
         _Float16* __restrict__ qph, _Float16* __restrict__ kbufh,
         _Float16* __restrict__ vh, unsigned* __restrict__ kmaxU,
         const int* __restrict__ ei, const int* __restrict__ coff,
         int* __restrict__ cursor, int2* __restrict__ crowR,
         const int* __restrict__ douti) {
  __shared__ __align__(16) _Float16 blds[12 * 2048];   // 48 KB
  const int blk = blockIdx.x;
  const int t = threadIdx.x;
  if (blk >= 942) {            // ---- CSR fill (overlaps GEMM) ----
    const int e = (blk - 942) * 512 + t;
    const int r = ei[e], c = ei[EE + e];
    const float w = rsqrtf((float)douti[r]);
    const int pos = atomicAdd(&cursor[c], 1);
    int2 rec; rec.x = r; rec.y = __float_as_int(w);
    crowR[coff[c] + pos] = rec;
    return;
  }
  const int y = blk / 157;
  const int h = y & 3;
  const int wid = t >> 6, lane = t & 63;
  const int g = lane >> 4, cl = lane & 15;
  const int rbase = (blk - y * 157) * 128 + wid * 16;
  int arow = rbase + cl; if (arow > NN - 1) arow = NN - 1;

  if (y < 4) {
    const _Float16* arp = feath + (size_t)arow * 256;
#pragma unroll
    for (int r = 0; r < 6; ++r) {
      const int idx = r * 4096 + t * 8;
      const int s = idx >> 11, wi = idx & 2047;
      gload16(Wf + (size_t)ct_of(s, 0, h, y) * 4096 + wi, &blds[idx]);
    }
    f16x8 Ah[4];
#pragma unroll
    for (int l = 0; l < 4; ++l)
      Ah[l] = *(const f16x8*)(arp + l * 32 + g * 8);
    __syncthreads();
    f16x8 Ah2[4];
#pragma unroll
    for (int l = 0; l < 4; ++l)
      Ah2[l] = *(const f16x8*)(arp + (l + 4) * 32 + g * 8);
    f32x4 acc[12];
#pragma unroll
    for (int s = 0; s < 12; ++s) acc[s] = (f32x4){0.f, 0.f, 0.f, 0.f};
#pragma unroll
    for (int ktl = 0; ktl < 4; ++ktl) {
#pragma unroll
      for (int s = 0; s < 12; ++s) {
        const f16x8 b = *(const f16x8*)&blds[s * 2048 + ktl * 512 + lane * 8];
        acc[s] = __builtin_amdgcn_mfma_f32_16x16x32_f16(Ah[ktl], b, acc[s], 0, 0, 0);
      }
    }
    __syncthreads();   // everyone done reading half0
#pragma unroll
    for (int r = 0; r < 6; ++r) {
      const int idx = r * 4096 + t * 8;
      const int s = idx >> 11, wi = idx & 2047;
      gload16(Wf + (size_t)ct_of(s, 0, h, y) * 4096 + 2048 + wi, &blds[idx]);
    }
    __syncthreads();   // half1 staged
#pragma unroll
    for (int ktl = 0; ktl < 4; ++ktl) {
#pragma unroll
      for (int s = 0; s < 12; ++s) {
        const f16x8 b = *(const f16x8*)&blds[s * 2048 + ktl * 512 + lane * 8];
        acc[s] = __builtin_amdgcn_mfma_f32_16x16x32_f16(Ah2[ktl], b, acc[s], 0, 0, 0);
      }
    }
    // ---- epilogue (wave-local) ----
#pragma unroll
    for (int s = 0; s < 12; ++s) {
      const float bb = bbig[ct_of(s, 0, h, y) * 16 + cl];
#pragma unroll
      for (int j = 0; j < 4; ++j) acc[s][j] += bb;
    }
    const float sc = rsqrtf(tau[0]) * SCALE_D4;
    const float h2 = 0.5f * sc * sc;
    float dsq[4], dsk[4];
#pragma unroll
    for (int j = 0; j < 4; ++j) {
      dsq[j] = acc[0][j] * acc[0][j] + acc[1][j] * acc[1][j] +
               acc[2][j] * acc[2][j] + acc[3][j] * acc[3][j];
      dsk[j] = acc[4][j] * acc[4][j] + acc[5][j] * acc[5][j] +
               acc[6][j] * acc[6][j] + acc[7][j] * acc[7][j];
    }
#pragma unroll
    for (int m = 1; m < 16; m <<= 1) {
#pragma unroll
      for (int j = 0; j < 4; ++j) {
        dsq[j] += __shfl_xor(dsq[j], m);
        dsk[j] += __shfl_xor(dsk[j], m);
      }
    }
    {  // xd_q -> qph (f16)
#pragma unroll
      for (int j = 0; j < 4; ++j) {
        const float x0 = acc[8][j], x1 = acc[9][j];
        float mv = fmaxf(x0, (cl < 14) ? x1 : -3.4e38f);
#pragma unroll
        for (int m = 1; m < 16; m <<= 1) mv = fmaxf(mv, __shfl_xor(mv, m));
        const float dg = h2 * dsq[j];
        const int r = rbase + 4 * g + j;
        if (r < NN) {
          _Float16* dst = qph + (size_t)r * 120 + h * 30;
          dst[cl] = (_Float16)(RATIO_F * (expf(x0 - dg - mv) + EPS_F));
          if (cl < 14)
            dst[16 + cl] = (_Float16)(RATIO_F * (expf(x1 - dg - mv) + EPS_F));
        }
      }
    }
    {  // xd_k -> kbufh (f16) + global head max
      float wmax = -3.4e38f;
#pragma unroll
      for (int j = 0; j < 4; ++j) {
        const float x0 = acc[10][j], x1 = acc[11][j];
        float mv = fmaxf(x0, (cl < 14) ? x1 : -3.4e38f);
#pragma unroll
        for (int m = 1; m < 16; m <<= 1) mv = fmaxf(mv, __shfl_xor(mv, m));
        wmax = fmaxf(wmax, mv);
        const float dg = h2 * dsk[j];
        const int r = rbase + 4 * g + j;
        if (r < NN) {
          _Float16* dst = kbufh + (size_t)r * 120 + h * 30;
          dst[cl] = (_Float16)(x0 - dg);
          if (cl < 14) dst[16 + cl] = (_Float16)(x1 - dg);
        }
      }
      wmax = fmaxf(wmax, __shfl_xor(wmax, 16));
      wmax = fmaxf(wmax, __shfl_xor(wmax, 32));
      if (lane == 0) atomicMax(&kmaxU[h], fenc(wmax));
    }
  } else {
    const _Float16* arp = zh16 + (size_t)arow * 256;
#pragma unroll
    for (int r = 0; r < 4; ++r) {
      const int idx = r * 4096 + t * 8;
      const int s = idx >> 11, wi = idx & 2047;
      gload16(Wf + (size_t)ct_of(s, 1, h, y) * 4096 + wi, &blds[idx]);
    }
    f16x8 Ah[4];
#pragma unroll
    for (int l = 0; l < 4; ++l)
      Ah[l] = *(const f16x8*)(arp + l * 32 + g * 8);
    __syncthreads();
    f16x8 Ah2[4];
#pragma unroll
    for (int l = 0; l < 4; ++l)
      Ah2[l] = *(const f16x8*)(arp + (l + 4) * 32 + g * 8);
    f32x4 acc[8];
#pragma unroll
    for (int s = 0; s < 8; ++s) acc[s] = (f32x4){0.f, 0.f, 0.f, 0.f};
#pragma unroll
    for (int ktl = 0; ktl < 4; ++ktl) {
#pragma unroll
      for (int s = 0; s < 8; ++s) {
        const f16x8 b = *(const f16x8*)&blds[s * 2048 + ktl * 512 + lane * 8];
        acc[s] = __builtin_amdgcn_mfma_f32_16x16x32_f16(Ah[ktl], b, acc[s], 0, 0, 0);
      }
    }
    __syncthreads();
#pragma unroll
    for (int r = 0; r < 4; ++r) {
      const int idx = r * 4096 + t * 8;
      const int s = idx >> 11, wi = idx & 2047;
      gload16(Wf + (size_t)ct_of(s, 1, h, y) * 4096 + 2048 + wi, &blds[idx]);
    }
    __syncthreads();
#pragma unroll
    for (int ktl = 0; ktl < 4; ++ktl) {
#pragma unroll
      for (int s = 0; s < 8; ++s) {
        const f16x8 b = *(const f16x8*)&blds[s * 2048 + ktl * 512 + lane * 8];
        acc[s] = __builtin_amdgcn_mfma_f32_16x16x32_f16(Ah2[ktl], b, acc[s], 0, 0, 0);
      }
    }
#pragma unroll
    for (int s = 0; s < 8; ++s) {
      const int ct = ct_of(s, 1, h, y);
      const float bb = bbig[ct * 16 + cl];
      const int colb = (ct - 32) * 16 + cl;
#pragma unroll
      for (int j = 0; j < 4; ++j) {
        const int r = rbase + 4 * g + j;
        if (r < NN) vh[(size_t)r * 256 + colb] = (_Float16)(acc[s][j] + bb);
      }
    }
  }
}

// ------------- K3a: per-chunk partials of kvs/ksum (no atomics) -------------
__global__ __launch_bounds__(256)
void k3_kvs(const _Float16* __restrict__ kbr, const _Float16* __restrict__ vh,
            const unsigned* __restrict__ kmaxU, float* __restrict__ partial) {
  __shared__ float kpch[128 * 32];
  __shared__ float vch[128 * 68];
  const int h = blockIdx.y;
  const int n0 = blockIdx.x * 128;
  const int cnt = min(128, NN - n0);
  const int t = threadIdx.x;
  const float mx = fdec(kmaxU[h]);
  const int m = t >> 3, dg = t & 7, d0 = dg * 8;
#pragma unroll
  for (int l = 0; l < 15; ++l) {
    const int flat = l * 256 + t;
    const int nl = flat / 30, mm = flat - nl * 30;
    kpch[nl * 32 + mm] = (nl < cnt)
        ? RATIO_F * (expf((float)kbr[(size_t)(n0 + nl) * 120 + h * 30 + mm] - mx) + EPS_F)
        : 0.f;
  }
#pragma unroll
  for (int l = 0; l < 8; ++l) {
    const int f4 = l * 256 + t;
    const int nl = f4 >> 4, dd = (f4 & 15) * 4;
    float4 vv = make_float4(0.f, 0.f, 0.f, 0.f);
    if (nl < cnt) {
      f16x4 u = *(const f16x4*)(vh + (size_t)(n0 + nl) * 256 + h * 64 + dd);
      vv = make_float4((float)u[0], (float)u[1], (float)u[2], (float)u[3]);
    }
    *(float4*)&vch[nl * 68 + dd] = vv;
  }
  __syncthreads();
  float acc[8] = {0, 0, 0, 0, 0, 0, 0, 0};
  float asum = 0.f;
  const int ms = (m < 30) ? m : 0;
  for (int nl = 0; nl < cnt; ++nl) {
    const float kv = kpch[nl * 32 + ms];
    const float4 va = *(const float4*)&vch[nl * 68 + d0];
    const float4 vb = *(const float4*)&vch[nl * 68 + d0 + 4];
    fma4(&acc[0], kv, va);
    fma4(&acc[4], kv, vb);
    asum += kv;
  }
  if (m < 30) {
    float* dst = partial + ((size_t)blockIdx.y * NCH + blockIdx.x) * 1952 + m * 64 + d0;
#pragma unroll
    for (int j = 0; j < 8; ++j) dst[j] = acc[j];
    if (dg == 0)
      partial[((size_t)blockIdx.y * NCH + blockIdx.x) * 1952 + 1920 + m] = asum;
  }
}

// =====================================================================
// K7g3b (merged): blocks 0-4999 gather via packed records -> aggh;
// 5000+ reduce partials -> kvs/ksum.
// =====================================================================
__global__ __launch_bounds__(256)
void k7g3b(const int* __restrict__ coff, const int2* __restrict__ crowR,
           const _Float16* __restrict__ vh, _Float16* __restrict__ aggh,
           const float* __restrict__ partial, float* __restrict__ kvs,
           float* __restrict__ ksum) {
  const int blk = blockIdx.x;
  if (blk >= 5000) {           // ---- k3b reduce ----
    const int idx = (blk - 5000) * 256 + threadIdx.x;
    if (idx >= 4 * 1952) return;
    const int h = idx / 1952, q = idx - h * 1952;
    float s = 0.f;
    for (int c = 0; c < NCH; ++c)
      s += partial[((size_t)h * NCH + c) * 1952 + q];
    if (q < 1920) kvs[h * 1920 + q] = s;
    else if (q < 1950) ksum[h * 30 + (q - 1920)] = s;
    return;
  }
  const int node = blk * 4 + (threadIdx.x >> 6);
  const int lane = threadIdx.x & 63;
  const int o0 = coff[node], o1 = coff[node + 1];
  float a0 = 0.f, a1 = 0.f, a2 = 0.f, a3 = 0.f;
  if (o1 > o0) {
    int e = o0;
    for (; e + 16 <= o1; e += 16) {
      int2 rc[16];
#pragma unroll
      for (int u = 0; u < 16; ++u) rc[u] = crowR[e + u];
#pragma unroll
      for (int u = 0; u < 16; ++u) {
        const float w = __int_as_float(rc[u].y);
        const f16x4 vv = *(const f16x4*)(vh + (size_t)rc[u].x * 256 + lane * 4);
        a0 = fmaf(w, (float)vv[0], a0);
        a1 = fmaf(w, (float)vv[1], a1);
        a2 = fmaf(w, (float)vv[2], a2);
        a3 = fmaf(w, (float)vv[3], a3);
      }
    }
    for (; e + 4 <= o1; e += 4) {
      int2 rc[4];
#pragma unroll
      for (int u = 0; u < 4; ++u) rc[u] = crowR[e + u];
#pragma unroll
      for (int u = 0; u < 4; ++u) {
        const float w = __int_as_float(rc[u].y);
        const f16x4 vv = *(const f16x4*)(vh + (size_t)rc[u].x * 256 + lane * 4);
        a0 = fmaf(w, (float)vv[0], a0);
        a1 = fmaf(w, (float)vv[1], a1);
        a2 = fmaf(w, (float)vv[2], a2);
        a3 = fmaf(w, (float)vv[3], a3);
      }
    }
    for (; e < o1; ++e) {
      const int2 rc = crowR[e];
      const float w = __int_as_float(rc.y);
      const f16x4 vv = *(const f16x4*)(vh + (size_t)rc.x * 256 + lane * 4);
      a0 = fmaf(w, (float)vv[0], a0);
      a1 = fmaf(w, (float)vv[1], a1);
      a2 = fmaf(w, (float)vv[2], a2);
      a3 = fmaf(w, (float)vv[3], a3);
    }
    const float rin = rsqrtf((float)(o1 - o0));
    a0 *= rin; a1 *= rin; a2 *= rin; a3 *= rin;
  }
  f16x4 st;
  st[0] = (_Float16)a0; st[1] = (_Float16)a1;
  st[2] = (_Float16)a2; st[3] = (_Float16)a3;
  *(f16x4*)(aggh + (size_t)node * 256 + lane * 4) = st;
}

// =====================================================================
// K48 (fused k4+k8m): 625 blocks x 256 thr, 32 rows/block.
// Phase A: attention num/den + sg*agg -> z-tile in LDS (stride 260).
// Barrier; stage WoFh (hi-only, 32 KB) into the kvsl/qpl union region.
// Phase B: out = zl @ Wo^T + bo via MFMA (16 MFMA/wave). No zh buffer.
// LDS: 48000 (union) + 480 + 16640 = 65.1 KB -> 2 blocks/CU.
// =====================================================================
__global__ __launch_bounds__(256)
void k48_out(const _Float16* __restrict__ qph, const float* __restrict__ kvs,
             const float* __restrict__ ksum, const _Float16* __restrict__ aggh,
             const float* __restrict__ bp, const _Float16* __restrict__ WoFh,
             const float* __restrict__ bo, float* __restrict__ out) {
  __shared__ __align__(16) char smem[48000];     // A: kvsl+qpl | B: wol
  __shared__ float ksl[120];
  __shared__ __align__(16) _Float16 zl[32 * 260];
  float* kvsl = (float*)smem;                    // 120*68 f32 = 32640 B
  float* qpl  = (float*)(smem + 32640);          // 32*120 f32 = 15360 B
  _Float16* wol = (_Float16*)smem;               // 16384 f16 = 32768 B
  const int t = threadIdx.x;
  const int n0 = blockIdx.x * 32;
  // ---- phase A: k4 attention math ----
#pragma unroll
  for (int l = 0; l < 30; ++l) {
    const int f = l * 256 + t;           // 7680
    const int hm = f >> 6, d = f & 63;
    kvsl[hm * 68 + d] = kvs[f];
  }
  if (t < 120) ksl[t] = ksum[t];
#pragma unroll
  for (int l = 0; l < 15; ++l) {
    const int f = l * 256 + t;           // 3840
    qpl[f] = (float)qph[(size_t)n0 * 120 + f];
  }
  __syncthreads();
  {
    const int nl = t >> 3, dg = t & 7, d0 = dg * 8;
    const float* qrow = &qpl[nl * 120];
    float den[4] = {0, 0, 0, 0};
    for (int m = 0; m < 30; ++m) {
#pragma unroll
      for (int hh = 0; hh < 4; ++hh)
        den[hh] = fmaf(qrow[hh * 30 + m], ksl[hh * 30 + m], den[hh]);
    }
    float acc[4][8] = {};
    for (int m = 0; m < 30; ++m) {
#pragma unroll
      for (int hh = 0; hh < 4; ++hh) {
        const float qv = qrow[hh * 30 + m];
        const float* kr = &kvsl[(hh * 30 + m) * 68 + d0];
        const float4 ka = *(const float4*)kr;
        const float4 kb = *(const float4*)(kr + 4);
        fma4(&acc[hh][0], qv, ka);
        fma4(&acc[hh][4], qv, kb);
      }
    }
    const size_t n = n0 + nl;
#pragma unroll
    for (int hh = 0; hh < 4; ++hh) {
      const float inv = 1.0f / den[hh];
      const float sg = 1.f / (1.f + expf(-bp[hh]));
      const f16x8 ag = *(const f16x8*)(aggh + n * 256 + hh * 64 + d0);
      f16x8 o;
#pragma unroll
      for (int jj = 0; jj < 8; ++jj)
        o[jj] = (_Float16)(acc[hh][jj] * inv + sg * (float)ag[jj]);
      *(f16x8*)&zl[nl * 260 + hh * 64 + d0] = o;
    }
  }
  __syncthreads();   // kvsl/qpl reads done, zl complete
  // ---- stage WoFh into union region ----
#pragma unroll
  for (int r = 0; r < 8; ++r) {
    const int idx = r * 256 + t;
    gload16(WoFh + (size_t)idx * 8, &wol[idx * 8]);
  }
  __syncthreads();
  // ---- phase B: out = zl @ Wo^T + bo ----
  {
    const int wid = t >> 6, lane = t & 63;
    const int g = lane >> 4, cl = lane & 15;
    const int rt = wid >> 1, ctp = (wid & 1) * 2;
    f16x8 Ah[8];
#pragma unroll
    for (int kt = 0; kt < 8; ++kt)
      Ah[kt] = *(const f16x8*)&zl[(rt * 16 + cl) * 260 + kt * 32 + g * 8];
    f32x4 acc0 = {0.f, 0.f, 0.f, 0.f}, acc1 = {0.f, 0.f, 0.f, 0.f};
#pragma unroll
    for (int kt = 0; kt < 8; ++kt) {
      const f16x8 b0 = *(const f16x8*)&wol[ctp * 4096 + kt * 512 + lane * 8];
      const f16x8 b1 = *(const f16x8*)&wol[(ctp + 1) * 4096 + kt * 512 + lane * 8];
      acc0 = __builtin_amdgcn_mfma_f32_16x16x32_f16(Ah[kt], b0, acc0, 0, 0, 0);
      acc1 = __builtin_amdgcn_mfma_f32_16x16x32_f16(Ah[kt], b1, acc1, 0, 0, 0);
    }
    const float bb0 = bo[ctp * 16 + cl];
    const float bb1 = bo[(ctp + 1) * 16 + cl];
#pragma unroll
    for (int j = 0; j < 4; ++j) {
      const int r = n0 + rt * 16 + 4 * g + j;
      out[(size_t)r * 64 + ctp * 16 + cl] = acc0[j] + bb0;
      out[(size_t)r * 64 + (ctp + 1) * 16 + cl] = acc1[j] + bb1;
    }
  }
}

// ------------- K6a: exclusive scan of in-degrees (1024 threads, int4) -------------
__global__ __launch_bounds__(1024)
void k6a_scan(const int* __restrict__ cnt, int* __restrict__ off) {
  __shared__ int s[1024];
  const int t = threadIdx.x;
  int4 v[5];
  int sum = 0;
  const int4* p4 = (const int4*)(cnt + t * 20);
#pragma unroll
  for (int i = 0; i < 5; ++i) {
    v[i] = p4[i];
    sum += v[i].x + v[i].y + v[i].z + v[i].w;
  }
  s[t] = sum;
  __syncthreads();
  for (int o = 1; o < 1024; o <<= 1) {
    const int add = (t >= o) ? s[t - o] : 0;
    __syncthreads();
    s[t] += add;
    __syncthreads();
  }
  int run = (t == 0) ? 0 : s[t - 1];
  if (t == 0) off[0] = 0;
  const int base = t * 20;
#pragma unroll
  for (int i = 0; i < 5; ++i) {
    const int vals[4] = {v[i].x, v[i].y, v[i].z, v[i].w};
#pragma unroll
    for (int j = 0; j < 4; ++j) {
      const int idx = base + i * 4 + j;
      if (idx < NN) { run += vals[j]; off[idx + 1] = run; }
    }
  }
}

extern "C" void kernel_launch(void* const* d_in, const int* in_sizes, int n_in,
                              void* d_out, int out_size, void* d_ws, size_t ws_size,
                              hipStream_t stream) {
  (void)in_sizes; (void)n_in; (void)out_size; (void)ws_size;
  const float* z    = (const float*)d_in[0];
  const float* feat = (const float*)d_in[1];
  const int*   ei   = (const int*)d_in[2];
  const float* tau  = (const float*)d_in[3];
  const float* Wq_w = (const float*)d_in[4];
  const float* Wq_b = (const float*)d_in[5];
  const float* Wk_w = (const float*)d_in[6];
  const float* Wk_b = (const float*)d_in[7];
  const float* Wv_w = (const float*)d_in[8];
  const float* Wv_b = (const float*)d_in[9];
  const float* Wo_w = (const float*)d_in[10];
  const float* Wo_b = (const float*)d_in[11];
  const float* bp   = (const float*)d_in[12];
  const float* proj = (const float*)d_in[13];
  float* out = (float*)d_out;

  char* p = (char*)d_ws;
  auto alloc = [&](size_t bytes) { char* r = p; p += (bytes + 255) & ~(size_t)255; return r; };
  _Float16* Wf    = (_Float16*)alloc((size_t)256 * 1024 * 2);
  _Float16* WoFh  = (_Float16*)alloc((size_t)64 * 256 * 2);
  float*    bbig  = (float*)alloc(1024 * 4);
  _Float16* feath = (_Float16*)alloc((size_t)NN * 256 * 2);
  _Float16* zh16  = (_Float16*)alloc((size_t)NN * 256 * 2);
  _Float16* vh    = (_Float16*)alloc((size_t)NN * 256 * 2);
  _Float16* aggh  = (_Float16*)alloc((size_t)NN * 256 * 2);
  _Float16* qph   = (_Float16*)alloc((size_t)NN * 120 * 2);
  _Float16* kbufh = (_Float16*)alloc((size_t)NN * 120 * 2);
  int2*     crowR = (int2*)alloc((size_t)EE * 8);
  int*      coff  = (int*)alloc((size_t)(NN + 1) * 4);
  float*    partial = (float*)alloc((size_t)4 * NCH * 1952 * 4);
  float*    kvs   = (float*)alloc(7680 * 4);
  float*    ksum  = (float*)alloc(120 * 4);
  // ---- contiguous zero-region ----
  char* z0 = p;
  unsigned* kmaxU = (unsigned*)alloc(16);
  int*      dini  = (int*)alloc((size_t)20480 * 4);   // padded for int4 scan
  int*      douti = (int*)alloc((size_t)NN * 4);
  int*      cursor= (int*)alloc((size_t)NN * 4);
  char* z1 = p;

  hipMemsetAsync(z0, 0, (size_t)(z1 - z0), stream);

  k0_build<<<1401 + 5000, 256, 0, stream>>>(
      Wq_w, Wk_w, Wv_w, Wq_b, Wk_b, Wv_b, proj, tau, Wo_w, ei, feat, z,
      Wf, bbig, WoFh, dini, douti, feath, zh16);
  k6a_scan<<<1, 1024, 0, stream>>>(dini, coff);
  k1m<<<1567, 512, 0, stream>>>(feath, zh16, Wf, bbig, tau, qph, kbufh, vh,
                                kmaxU, ei, coff, cursor, crowR, douti);
  k3_kvs<<<dim3(NCH, 4), 256, 0, stream>>>(kbufh, vh, kmaxU, partial);
  k7g3b<<<5000 + (4 * 1952 + 255) / 256, 256, 0, stream>>>(
      coff, crowR, vh, aggh, partial, kvs, ksum);
  k48_out<<<NN / 32, 256, 0, stream>>>(qph, kvs, ksum, aggh, bp, WoFh, Wo_b, out);
}